// Round 2
// baseline (121.900 us; speedup 1.0000x reference)
//
#include <hip/hip_runtime.h>

#define MASK_HW 28
#define OUT_H 512
#define OUT_W 512
#define N_INST 100
#define ROWS_PER_TILE 16

// ---------------------------------------------------------------------------
// Kernel Z: stream zeros over the whole output. Mirrors fillBufferAligned:
// grid-stride float4 stores, minimal per-store VALU. ~80% HBM peak expected.
// ---------------------------------------------------------------------------
__global__ __launch_bounds__(256) void zero_fill_kernel(float4* __restrict__ out, int n4)
{
    const int stride = gridDim.x * 256;
    const float4 z = make_float4(0.f, 0.f, 0.f, 0.f);
    for (int i = blockIdx.x * 256 + threadIdx.x; i < n4; i += stride)
        out[i] = z;
}

// ---------------------------------------------------------------------------
// Kernel B: compute bilinear samples only inside each instance's box
// rectangle (conservatively expanded; per-pixel guard writes 0 on the rim,
// which the zero-fill already covered). Grid: (instance, row-tile).
// ---------------------------------------------------------------------------
__global__ __launch_bounds__(256) void paste_box_kernel(
    const float* __restrict__ masks,   // [N,1,28,28]
    const float* __restrict__ boxes,   // [N,4]
    float* __restrict__ out)           // [N,1,512,512]
{
    const int n   = blockIdx.x;
    const int tid = threadIdx.x;

    const float bx0 = boxes[4 * n + 0];
    const float by0 = boxes[4 * n + 1];
    const float bx1 = boxes[4 * n + 2] + 1e-5f;
    const float by1 = boxes[4 * n + 3] + 1e-5f;
    const float sxf = 28.0f / (bx1 - bx0);   // mask coord per output px
    const float syf = 28.0f / (by1 - by0);
    const float inv_sx = (bx1 - bx0) * (1.0f / 28.0f);
    const float inv_sy = (by1 - by0) * (1.0f / 28.0f);

    // nonzero support: xs in (-1,28)  <=>  x in (xlo, xhi), row-independent
    const float xlo = bx0 - 0.5f - 0.5f * inv_sx;
    const float xhi = bx0 - 0.5f + 28.5f * inv_sx;
    const float ylo = by0 - 0.5f - 0.5f * inv_sy;
    const float yhi = by0 - 0.5f + 28.5f * inv_sy;

    const int clo = max(0, (int)floorf(xlo));            // conservative
    const int chi = min(OUT_W, (int)ceilf(xhi) + 1);
    const int rlo = max(0, (int)floorf(ylo));
    const int rhi = min(OUT_H, (int)ceilf(yhi) + 1);

    // this block's row slice
    const int r0 = rlo + blockIdx.y * ROWS_PER_TILE;
    if (r0 >= rhi) return;                                // uniform early-out
    const int r1 = min(r0 + ROWS_PER_TILE, rhi);

    // stage mask into zero-padded LDS: mask at [1..28][1..28]
    __shared__ float sm[MASK_HW + 2][MASK_HW + 5];        // 30 x 33
    for (int i = tid; i < (MASK_HW + 2) * (MASK_HW + 5); i += 256)
        ((float*)sm)[i] = 0.0f;
    __syncthreads();
    const float* mptr = masks + (size_t)n * (MASK_HW * MASK_HW);
    for (int i = tid; i < MASK_HW * MASK_HW; i += 256) {
        const int r = i / MASK_HW;
        const int c = i - r * MASK_HW;
        sm[r + 1][c + 1] = mptr[i];
    }
    __syncthreads();

    float* outn = out + (size_t)n * (OUT_H * OUT_W);

    for (int row = r0; row < r1; ++row) {
        const float ys = ((float)row + 0.5f - by0) * syf - 0.5f;
        if (ys <= -1.0f || ys >= 28.0f) continue;
        const float y0f = floorf(ys);
        const int   y0i = (int)y0f;                       // [-1, 27]
        const float wy1 = ys - y0f;
        const float wy0 = 1.0f - wy1;
        const float* rA = &sm[y0i + 1][0];
        const float* rB = &sm[y0i + 2][0];

        for (int c = clo + tid; c < chi; c += 256) {
            const float xs = ((float)c + 0.5f - bx0) * sxf - 0.5f;
            float val = 0.0f;
            if (xs > -1.0f && xs < 28.0f) {
                const float x0f = floorf(xs);
                const int   x0i = (int)x0f;               // [-1, 27]
                const float wx1 = xs - x0f;
                const float wx0 = 1.0f - wx1;
                val = wy0 * (wx0 * rA[x0i + 1] + wx1 * rA[x0i + 2]) +
                      wy1 * (wx0 * rB[x0i + 1] + wx1 * rB[x0i + 2]);
            }
            outn[(size_t)row * OUT_W + c] = val;
        }
    }
}

extern "C" void kernel_launch(void* const* d_in, const int* in_sizes, int n_in,
                              void* d_out, int out_size, void* d_ws, size_t ws_size,
                              hipStream_t stream) {
    const float* masks = (const float*)d_in[0];   // [100,1,28,28] fp32
    const float* boxes = (const float*)d_in[1];   // [100,4] fp32
    float* out = (float*)d_out;                   // [100,1,512,512] fp32

    const int n4 = N_INST * OUT_H * OUT_W / 4;    // 6,553,600 float4
    zero_fill_kernel<<<dim3(2048), dim3(256), 0, stream>>>((float4*)out, n4);

    // max box extent: wh <= 256 -> <= 257 rows + conservative rim -> 17 tiles
    paste_box_kernel<<<dim3(N_INST, 17), dim3(256), 0, stream>>>(masks, boxes, out);
}